// Round 1
// 421.419 us; speedup vs baseline: 1.1336x; 1.1336x over previous
//
#include <hip/hip_runtime.h>
#include <hip/hip_bf16.h>
#include <math.h>

// Problem constants
#define BB    2
#define NN    1024
#define PAST  1024
#define KVL   2048            // PAST + NN
#define DIM   2048
#define HEADS 16
#define DH    128
#define INNER 2048            // HEADS*DH
#define NQKV  6144            // 3*INNER
#define TOK   2048            // BB*NN
#define LN_EPS 1e-5f

typedef __attribute__((ext_vector_type(8))) short   short8;   // 8 bf16 (4 VGPR)
typedef __attribute__((ext_vector_type(4))) float   f32x4;
typedef __attribute__((ext_vector_type(8))) unsigned short us8;
typedef __attribute__((ext_vector_type(4))) unsigned short us4;
typedef unsigned short us;

__device__ __forceinline__ float bfbits2f(us u) {
    return __uint_as_float(((unsigned int)u) << 16);
}
__device__ __forceinline__ us f2bfb(float f) {
    union { __hip_bfloat16 h; us u; } cv;
    cv.h = __float2bfloat16(f);           // RNE
    return cv.u;
}
__device__ __forceinline__ us8 pack8u(float4 a, float4 b) {
    us8 r;
    r[0] = f2bfb(a.x); r[1] = f2bfb(a.y); r[2] = f2bfb(a.z); r[3] = f2bfb(a.w);
    r[4] = f2bfb(b.x); r[5] = f2bfb(b.y); r[6] = f2bfb(b.z); r[7] = f2bfb(b.w);
    return r;
}

// async global->LDS, 16B per lane. LDS dest must be linear (base + lane*16);
// swizzled layouts are achieved by pre-swizzling the GLOBAL source address.
__device__ __forceinline__ void gload_lds16(const void* gsrc, void* ldst) {
    __builtin_amdgcn_global_load_lds(
        (const __attribute__((address_space(1))) void*)gsrc,
        (__attribute__((address_space(3))) void*)ldst, 16, 0, 0);
}

// ---------------------------------------------------------------------------
// K0: transpose + cast: dst[C][R] (bf16) <- src[R][C] (f32). 64x64 tiles.
// ---------------------------------------------------------------------------
__global__ __launch_bounds__(256) void transp_kernel(
    const float* __restrict__ src, us* __restrict__ dst, int R, int C)
{
    const int c0 = blockIdx.x * 64;
    const int r0 = blockIdx.y * 64;
    const int tid = threadIdx.x;

    __shared__ us T[64][68];

    #pragma unroll
    for (int e = 0; e < 4; e++) {
        int idx = tid + e * 256;
        int jr  = idx >> 4;               // row within tile
        int c4  = (idx & 15) * 4;
        float4 v = *reinterpret_cast<const float4*>(
            src + (size_t)(r0 + jr) * C + c0 + c4);
        us4 w;
        w[0] = f2bfb(v.x); w[1] = f2bfb(v.y); w[2] = f2bfb(v.z); w[3] = f2bfb(v.w);
        *reinterpret_cast<us4*>(&T[jr][c4]) = w;
    }
    __syncthreads();

    #pragma unroll
    for (int e = 0; e < 4; e++) {
        int idx = tid + e * 256;
        int d   = idx >> 4;               // col within tile (dst row)
        int k4  = (idx & 15) * 4;
        us4 w;
        w[0] = T[k4 + 0][d];
        w[1] = T[k4 + 1][d];
        w[2] = T[k4 + 2][d];
        w[3] = T[k4 + 3][d];
        *reinterpret_cast<us4*>(dst + (size_t)(c0 + d) * R + r0 + k4) = w;
    }
}

// ---------------------------------------------------------------------------
// K1: LayerNorm over DIM=2048 -> bf16. One block per token.
// ---------------------------------------------------------------------------
__global__ __launch_bounds__(256) void ln_kernel(
    const float* __restrict__ x, const float* __restrict__ g,
    const float* __restrict__ b, us* __restrict__ xn)
{
    const int t   = blockIdx.x;
    const int tid = threadIdx.x;
    const size_t base = (size_t)t * DIM;

    float4 p0 = reinterpret_cast<const float4*>(x + base)[tid * 2 + 0];
    float4 p1 = reinterpret_cast<const float4*>(x + base)[tid * 2 + 1];
    float v[8] = {p0.x, p0.y, p0.z, p0.w, p1.x, p1.y, p1.z, p1.w};

    float s1 = 0.f, s2 = 0.f;
    #pragma unroll
    for (int i = 0; i < 8; i++) { s1 += v[i]; s2 += v[i] * v[i]; }

    #pragma unroll
    for (int off = 32; off; off >>= 1) {
        s1 += __shfl_xor(s1, off);
        s2 += __shfl_xor(s2, off);
    }
    __shared__ float red1[4], red2[4];
    if ((tid & 63) == 0) { red1[tid >> 6] = s1; red2[tid >> 6] = s2; }
    __syncthreads();
    float S1 = red1[0] + red1[1] + red1[2] + red1[3];
    float S2 = red2[0] + red2[1] + red2[2] + red2[3];
    const float inv = 1.0f / (float)DIM;
    float mu  = S1 * inv;
    float var = S2 * inv - mu * mu;
    float rstd = rsqrtf(var + LN_EPS);

    const int d0 = tid * 8;
    float4 oa, ob;
    oa.x = (v[0] - mu) * rstd * g[d0 + 0] + b[d0 + 0];
    oa.y = (v[1] - mu) * rstd * g[d0 + 1] + b[d0 + 1];
    oa.z = (v[2] - mu) * rstd * g[d0 + 2] + b[d0 + 2];
    oa.w = (v[3] - mu) * rstd * g[d0 + 3] + b[d0 + 3];
    ob.x = (v[4] - mu) * rstd * g[d0 + 4] + b[d0 + 4];
    ob.y = (v[5] - mu) * rstd * g[d0 + 5] + b[d0 + 5];
    ob.z = (v[6] - mu) * rstd * g[d0 + 6] + b[d0 + 6];
    ob.w = (v[7] - mu) * rstd * g[d0 + 7] + b[d0 + 7];

    *reinterpret_cast<us8*>(xn + base + d0) = pack8u(oa, ob);
}

// ---------------------------------------------------------------------------
// K2/K5: MFMA GEMM (B^T layout):  C[M][N] = A[M][K] @ Bt[N][K]^T  (bf16 in)
// ---------------------------------------------------------------------------
template<bool OUT_BF16>
__global__ __launch_bounds__(256) void gemm_bt_kernel(
    const us* __restrict__ A, const us* __restrict__ Bt,
    void* __restrict__ Cout, int M, int N, int K)
{
    __shared__ us As[128][40];
    __shared__ us Bs[128][40];

    const int tid  = threadIdx.x;
    const int wave = tid >> 6, lane = tid & 63;
    const int quad = lane >> 4, l16 = lane & 15;
    const int wm = wave & 1, wn = wave >> 1;
    const int m0 = blockIdx.y * 128, n0 = blockIdx.x * 128;

    f32x4 acc[4][4];
    #pragma unroll
    for (int i = 0; i < 4; i++)
        #pragma unroll
        for (int j = 0; j < 4; j++)
            #pragma unroll
            for (int r = 0; r < 4; r++) acc[i][j][r] = 0.f;

    const int s_row = tid >> 2;          // 0..63
    const int s_c8  = (tid & 3) * 8;     // 0,8,16,24

    const us* pa0 = A  + (size_t)(m0 + s_row)      * K + s_c8;
    const us* pa1 = A  + (size_t)(m0 + 64 + s_row) * K + s_c8;
    const us* pb0 = Bt + (size_t)(n0 + s_row)      * K + s_c8;
    const us* pb1 = Bt + (size_t)(n0 + 64 + s_row) * K + s_c8;

    for (int k0 = 0; k0 < K; k0 += 32) {
        us8 a0 = *reinterpret_cast<const us8*>(pa0 + k0);
        us8 a1 = *reinterpret_cast<const us8*>(pa1 + k0);
        us8 b0 = *reinterpret_cast<const us8*>(pb0 + k0);
        us8 b1 = *reinterpret_cast<const us8*>(pb1 + k0);

        __syncthreads();   // previous tile fully consumed
        *reinterpret_cast<us8*>(&As[s_row][s_c8])      = a0;
        *reinterpret_cast<us8*>(&As[64 + s_row][s_c8]) = a1;
        *reinterpret_cast<us8*>(&Bs[s_row][s_c8])      = b0;
        *reinterpret_cast<us8*>(&Bs[64 + s_row][s_c8]) = b1;
        __syncthreads();

        short8 af[4], bf[4];
        #pragma unroll
        for (int mi = 0; mi < 4; mi++)
            af[mi] = *reinterpret_cast<const short8*>(
                &As[wm * 64 + mi * 16 + l16][quad * 8]);
        #pragma unroll
        for (int ni = 0; ni < 4; ni++)
            bf[ni] = *reinterpret_cast<const short8*>(
                &Bs[wn * 64 + ni * 16 + l16][quad * 8]);

        #pragma unroll
        for (int mi = 0; mi < 4; mi++)
            #pragma unroll
            for (int ni = 0; ni < 4; ni++)
                acc[mi][ni] = __builtin_amdgcn_mfma_f32_16x16x32_bf16(
                    af[mi], bf[ni], acc[mi][ni], 0, 0, 0);
    }

    // epilogue: C/D layout col=l16, row=quad*4+r
    #pragma unroll
    for (int mi = 0; mi < 4; mi++) {
        #pragma unroll
        for (int r = 0; r < 4; r++) {
            size_t row = (size_t)(m0 + wm * 64 + mi * 16 + quad * 4 + r);
            #pragma unroll
            for (int ni = 0; ni < 4; ni++) {
                size_t col = n0 + wn * 64 + ni * 16 + l16;
                if (OUT_BF16)
                    ((us*)Cout)[row * N + col] = f2bfb(acc[mi][ni][r]);
                else
                    ((float*)Cout)[row * N + col] = acc[mi][ni][r];
            }
        }
    }
}

// ---------------------------------------------------------------------------
// K3: RoPE + KV cache assembly. qkv is bf16; outputs f32 + bf16 K copy.
// ---------------------------------------------------------------------------
__global__ __launch_bounds__(256) void rope_kernel(
    const float* __restrict__ past_k, const float* __restrict__ past_v,
    us* __restrict__ qkv, float* __restrict__ out_k, float* __restrict__ out_v,
    us* __restrict__ Kbf)
{
    const int tid  = threadIdx.x;
    const int pid  = blockIdx.x * 4 + (tid >> 6);
    const int lane = tid & 63;

    const int b   = pid / (HEADS * KVL);
    const int rem = pid - b * (HEADS * KVL);
    const int h   = rem / KVL;
    const int pos = rem - h * KVL;

    const float invf = exp2f((float)lane * (-13.287712379549449f / 64.0f));
    float sn, cs;
    sincosf((float)pos * invf, &sn, &cs);

    const size_t obase = ((size_t)(b * HEADS + h) * KVL + pos) * DH + 2 * lane;

    float k0, k1;
    if (pos < PAST) {
        const size_t pbase = ((size_t)(b * HEADS + h) * PAST + pos) * DH + 2 * lane;
        k0 = past_k[pbase];
        k1 = past_k[pbase + 1];
    } else {
        const int t = b * NN + (pos - PAST);
        const us* qp = qkv + (size_t)t * NQKV + INNER + h * DH + 2 * lane;
        k0 = bfbits2f(qp[0]); k1 = bfbits2f(qp[1]);
    }
    float kr0 = k0 * cs - k1 * sn;
    float kr1 = k1 * cs + k0 * sn;
    out_k[obase]     = kr0;
    out_k[obase + 1] = kr1;
    Kbf[obase]       = f2bfb(kr0);
    Kbf[obase + 1]   = f2bfb(kr1);

    if (pos < PAST) {
        const size_t pbase = ((size_t)(b * HEADS + h) * PAST + pos) * DH + 2 * lane;
        out_v[obase]     = past_v[pbase];
        out_v[obase + 1] = past_v[pbase + 1];
    } else {
        const int t = b * NN + (pos - PAST);
        const us* vp = qkv + (size_t)t * NQKV + 2 * INNER + h * DH + 2 * lane;
        out_v[obase]     = bfbits2f(vp[0]);
        out_v[obase + 1] = bfbits2f(vp[1]);
    }

    if (pos >= PAST) {
        const int t = b * NN + (pos - PAST);
        us* qq = qkv + (size_t)t * NQKV + h * DH + 2 * lane;
        float q0 = bfbits2f(qq[0]), q1 = bfbits2f(qq[1]);
        qq[0] = f2bfb(q0 * cs - q1 * sn);
        qq[1] = f2bfb(q1 * cs + q0 * sn);
    }
}

// ---------------------------------------------------------------------------
// K3b: V transpose to bf16: Vtg[bh][d][kv] <- bf16(out_v[bh][kv][d])
// ---------------------------------------------------------------------------
__global__ __launch_bounds__(256) void vtrans_kernel(
    const float* __restrict__ Vc, us* __restrict__ Vtg)
{
    const int jb = blockIdx.x;
    const int db = blockIdx.y;
    const int bh = blockIdx.z;
    const int tid = threadIdx.x;

    __shared__ us T[64][68];

    const float* src = Vc + ((size_t)bh * KVL + jb * 64) * DH + db * 64;
    #pragma unroll
    for (int e = 0; e < 4; e++) {
        int idx = tid + e * 256;
        int jr  = idx >> 4;
        int c4  = (idx & 15) * 4;
        float4 v = *reinterpret_cast<const float4*>(src + (size_t)jr * DH + c4);
        us4 w;
        w[0] = f2bfb(v.x); w[1] = f2bfb(v.y); w[2] = f2bfb(v.z); w[3] = f2bfb(v.w);
        *reinterpret_cast<us4*>(&T[jr][c4]) = w;
    }
    __syncthreads();

    us* dst = Vtg + ((size_t)bh * DH + db * 64) * KVL + jb * 64;
    #pragma unroll
    for (int e = 0; e < 4; e++) {
        int idx = tid + e * 256;
        int d   = idx >> 4;
        int k4  = (idx & 15) * 4;
        us4 w;
        w[0] = T[k4 + 0][d];
        w[1] = T[k4 + 1][d];
        w[2] = T[k4 + 2][d];
        w[3] = T[k4 + 3][d];
        *reinterpret_cast<us4*>(dst + (size_t)d * KVL + k4) = w;
    }
}

// ---------------------------------------------------------------------------
// K4: MFMA flash attention. 64 queries x (h,b) per block; 4 waves; KV chunk 64.
// K/V staged bf16 via global_load_lds into XOR-swizzled LDS (pre-swizzled
// global source, linear LDS dest). Double-buffered; mid-chunk barrier is a
// raw s_barrier + lgkmcnt(0) so stage loads stay in flight across it.
// Swizzle: phys_byte = row*ROWB + (col_byte ^ ((row&7)<<4)).
// ---------------------------------------------------------------------------
__global__ __launch_bounds__(256) void attn_mfma_kernel(
    const us* __restrict__ qkv,               // [TOK][NQKV] bf16, q roped
    const us* __restrict__ Kbf,               // [bh][KVL][DH] bf16 (roped)
    const us* __restrict__ Vtg,               // [bh][DH][KVL] bf16
    us* __restrict__ Ao)                      // [TOK][INNER] bf16
{
    const int qt   = blockIdx.x;
    const int h    = blockIdx.y;
    const int b    = blockIdx.z;
    const int tid  = threadIdx.x;
    const int wave = tid >> 6;
    const int lane = tid & 63;
    const int quad = lane >> 4;
    const int l16  = lane & 15;

    __shared__ us Ks[2][64 * 128];   // 16 KB x2, swizzled rows of 256 B
    __shared__ us Vt[2][128 * 64];   // 16 KB x2, swizzled rows of 128 B
    __shared__ us Pb[64][72];        // 9 KB

    // Q A-fragments: direct bf16 loads
    short8 qf[4];
    {
        const int qrow = qt * 64 + wave * 16 + l16;
        const us* qp = qkv + (size_t)(b * NN + qrow) * NQKV + h * DH;
        #pragma unroll
        for (int ks = 0; ks < 4; ks++)
            qf[ks] = *reinterpret_cast<const short8*>(qp + ks * 32 + quad * 8);
    }

    f32x4 Oacc[8];
    #pragma unroll
    for (int t = 0; t < 8; t++)
        #pragma unroll
        for (int r = 0; r < 4; r++) Oacc[t][r] = 0.f;
    float mrow[4] = {-INFINITY, -INFINITY, -INFINITY, -INFINITY};
    float lrow[4] = {0.f, 0.f, 0.f, 0.f};

    const us* kptr = Kbf + (size_t)(b * HEADS + h) * KVL * DH;
    const us* vtb  = Vtg + (size_t)(b * HEADS + h) * DH * KVL;
    const float scale = 0.08838834764831845f;
    const int qg = PAST + qt * 64 + wave * 16 + quad * 4;
    const int nch = 17 + qt;

    auto stage = [&](int j0, int buf) {
        // K chunk: 64 rows x 256 B
        #pragma unroll
        for (int e = 0; e < 4; e++) {
            int phys = (e * 256 + tid) * 16;
            int row  = phys >> 8;
            int col  = (phys & 255) ^ ((row & 7) << 4);
            gload_lds16((const char*)(kptr + (size_t)(j0 + row) * DH) + col,
                        (char*)&Ks[buf][0] + phys);
        }
        // V chunk: 128 rows x 128 B
        #pragma unroll
        for (int e = 0; e < 4; e++) {
            int phys = (e * 256 + tid) * 16;
            int row  = phys >> 7;
            int col  = (phys & 127) ^ ((row & 7) << 4);
            gload_lds16((const char*)(vtb + (size_t)row * KVL + j0) + col,
                        (char*)&Vt[buf][0] + phys);
        }
    };

    stage(0, 0);
    __syncthreads();            // drains vmcnt -> chunk 0 resident

    int cur = 0;
    for (int c = 0; c < nch; c++) {
        const int j0 = c * 64;
        if (c + 1 < nch) stage(j0 + 64, cur ^ 1);   // async prefetch

        // ---- QK^T ----
        f32x4 S[4];
        #pragma unroll
        for (int t = 0; t < 4; t++)
            #pragma unroll
            for (int r = 0; r < 4; r++) S[t][r] = 0.f;
        __builtin_amdgcn_s_setprio(1);
        #pragma unroll
        for (int ks = 0; ks < 4; ks++) {
            #pragma unroll
            for (int t = 0; t < 4; t++) {
                int row  = t * 16 + l16;
                int colb = ks * 64 + quad * 16;
                const char* p = (const char*)&Ks[cur][0] +
                                row * 256 + (colb ^ ((row & 7) << 4));
                short8 kb = *reinterpret_cast<const short8*>(p);
                S[t] = __builtin_amdgcn_mfma_f32_16x16x32_bf16(qf[ks], kb, S[t], 0, 0, 0);
            }
        }
        __builtin_amdgcn_s_setprio(0);

        // ---- mask + online softmax ----
        #pragma unroll
        for (int t = 0; t < 4; t++) {
            int kg = j0 + t * 16 + l16;
            #pragma unroll
            for (int r = 0; r < 4; r++) {
                float s = S[t][r] * scale;
                S[t][r] = (kg <= qg + r) ? s : -INFINITY;
            }
        }

        float alpha[4];
        #pragma unroll
        for (int r = 0; r < 4; r++) {
            float mx = fmaxf(fmaxf(S[0][r], S[1][r]), fmaxf(S[2][r], S[3][r]));
            mx = fmaxf(mx, __shfl_xor(mx, 1));
            mx = fmaxf(mx, __shfl_xor(mx, 2));
            mx = fmaxf(mx, __shfl_xor(mx, 4));
            mx = fmaxf(mx, __shfl_xor(mx, 8));
            float nm = fmaxf(mrow[r], mx);
            alpha[r] = __expf(mrow[r] - nm);
            mrow[r] = nm;
            float rs = 0.f;
            #pragma unroll
            for (int t = 0; t < 4; t++) {
                float p = __expf(S[t][r] - nm);
                S[t][r] = p;
                rs += p;
            }
            rs += __shfl_xor(rs, 1);
            rs += __shfl_xor(rs, 2);
            rs += __shfl_xor(rs, 4);
            rs += __shfl_xor(rs, 8);
            lrow[r] = lrow[r] * alpha[r] + rs;
        }

        #pragma unroll
        for (int t = 0; t < 8; t++)
            #pragma unroll
            for (int r = 0; r < 4; r++) Oacc[t][r] *= alpha[r];

        // ---- P -> LDS ----  (prev chunk's Pb reads finished at end barrier)
        #pragma unroll
        for (int t = 0; t < 4; t++)
            #pragma unroll
            for (int r = 0; r < 4; r++)
                Pb[wave * 16 + quad * 4 + r][t * 16 + l16] = f2bfb(S[t][r]);

        // mid barrier: LDS-only drain; global_load_lds stays in flight
        asm volatile("s_waitcnt lgkmcnt(0)" ::: "memory");
        __builtin_amdgcn_s_barrier();
        __builtin_amdgcn_sched_barrier(0);

        // ---- PV ----
        __builtin_amdgcn_s_setprio(1);
        #pragma unroll
        for (int kh = 0; kh < 2; kh++) {
            short8 pa = *reinterpret_cast<const short8*>(
                &Pb[wave * 16 + l16][kh * 32 + quad * 8]);
            #pragma unroll
            for (int t2 = 0; t2 < 8; t2++) {
                int row  = t2 * 16 + l16;
                int colb = kh * 64 + quad * 16;
                const char* p = (const char*)&Vt[cur][0] +
                                row * 128 + (colb ^ ((row & 7) << 4));
                short8 vb = *reinterpret_cast<const short8*>(p);
                Oacc[t2] = __builtin_amdgcn_mfma_f32_16x16x32_bf16(pa, vb, Oacc[t2], 0, 0, 0);
            }
        }
        __builtin_amdgcn_s_setprio(0);

        __syncthreads();        // full drain: prefetch landed, Pb/Vt reads done
        cur ^= 1;
    }

    float invl[4];
    #pragma unroll
    for (int r = 0; r < 4; r++) invl[r] = 1.f / lrow[r];
    const int row0 = b * NN + qt * 64 + wave * 16 + quad * 4;
    #pragma unroll
    for (int r = 0; r < 4; r++) {
        us* dst = Ao + (size_t)(row0 + r) * INNER + h * DH + l16;
        #pragma unroll
        for (int t2 = 0; t2 < 8; t2++)
            dst[t2 * 16] = f2bfb(Oacc[t2][r] * invl[r]);
    }
}

// ---------------------------------------------------------------------------
extern "C" void kernel_launch(void* const* d_in, const int* in_sizes, int n_in,
                              void* d_out, int out_size, void* d_ws, size_t ws_size,
                              hipStream_t stream)
{
    const float* x      = (const float*)d_in[0];
    const float* past_k = (const float*)d_in[1];
    const float* past_v = (const float*)d_in[2];
    // d_in[3] = mask (unused; computed analytically)
    const float* w_qkv  = (const float*)d_in[4];
    const float* w_out  = (const float*)d_in[5];
    const float* ln_g   = (const float*)d_in[6];
    const float* ln_b   = (const float*)d_in[7];

    float* out   = (float*)d_out;                      // [B,N,DIM]
    float* out_k = out   + (size_t)BB * NN * DIM;      // [B,H,KVL,DH]
    float* out_v = out_k + (size_t)BB * HEADS * KVL * DH;

    // ws (bf16 buffers), 80 MB total:
    us* xn   = (us*)d_ws;                              // [TOK][DIM]     8 MB
    us* qkv  = xn  + (size_t)TOK * DIM;                // [TOK][NQKV]   24 MB
    us* Wqt  = qkv + (size_t)TOK * NQKV;               // [NQKV][DIM]   24 MB
    us* Wot  = Wqt + (size_t)NQKV * DIM;               // [DIM][INNER]   8 MB
    us* Vtg  = Wot + (size_t)DIM * INNER;              // [bh][DH][KVL] 16 MB
    us* attn = xn;   // alias: xn dead after qkv GEMM  // [TOK][INNER]   8 MB
    us* Kbf  = Wqt;  // alias: Wqt dead after qkv GEMM // [bh][KVL][DH] 16.7 MB

    transp_kernel<<<dim3(NQKV / 64, DIM / 64), 256, 0, stream>>>(
        w_qkv, Wqt, DIM, NQKV);
    transp_kernel<<<dim3(DIM / 64, INNER / 64), 256, 0, stream>>>(
        w_out, Wot, INNER, DIM);

    ln_kernel<<<TOK, 256, 0, stream>>>(x, ln_g, ln_b, xn);

    gemm_bt_kernel<true><<<dim3(NQKV / 128, TOK / 128), 256, 0, stream>>>(
        xn, Wqt, (void*)qkv, TOK, NQKV, DIM);

    rope_kernel<<<(BB * HEADS * KVL) / 4, 256, 0, stream>>>(
        past_k, past_v, qkv, out_k, out_v, Kbf);

    vtrans_kernel<<<dim3(KVL / 64, DH / 64, BB * HEADS), 256, 0, stream>>>(
        out_v, Vtg);

    attn_mfma_kernel<<<dim3(NN / 64, HEADS, BB), 256, 0, stream>>>(
        qkv, Kbf, Vtg, attn);

    gemm_bt_kernel<false><<<dim3(DIM / 128, TOK / 128), 256, 0, stream>>>(
        attn, Wot, (void*)out, TOK, DIM, INNER);
}

// Round 2
// 381.270 us; speedup vs baseline: 1.2530x; 1.1053x over previous
//
#include <hip/hip_runtime.h>
#include <hip/hip_bf16.h>
#include <math.h>

// Problem constants
#define BB    2
#define NN    1024
#define PAST  1024
#define KVL   2048            // PAST + NN
#define DIM   2048
#define HEADS 16
#define DH    128
#define INNER 2048            // HEADS*DH
#define NQKV  6144            // 3*INNER
#define TOK   2048            // BB*NN
#define LN_EPS 1e-5f

typedef __attribute__((ext_vector_type(8))) short   short8;   // 8 bf16 (4 VGPR)
typedef __attribute__((ext_vector_type(4))) float   f32x4;
typedef __attribute__((ext_vector_type(8))) unsigned short us8;
typedef __attribute__((ext_vector_type(4))) unsigned short us4;
typedef unsigned short us;

__device__ __forceinline__ float bfbits2f(us u) {
    return __uint_as_float(((unsigned int)u) << 16);
}
__device__ __forceinline__ us f2bfb(float f) {
    union { __hip_bfloat16 h; us u; } cv;
    cv.h = __float2bfloat16(f);           // RNE
    return cv.u;
}
__device__ __forceinline__ us8 pack8u(float4 a, float4 b) {
    us8 r;
    r[0] = f2bfb(a.x); r[1] = f2bfb(a.y); r[2] = f2bfb(a.z); r[3] = f2bfb(a.w);
    r[4] = f2bfb(b.x); r[5] = f2bfb(b.y); r[6] = f2bfb(b.z); r[7] = f2bfb(b.w);
    return r;
}

// async global->LDS, 16B per lane. LDS dest must be linear (base + lane*16);
// swizzled layouts are achieved by pre-swizzling the GLOBAL source address.
__device__ __forceinline__ void gload_lds16(const void* gsrc, void* ldst) {
    __builtin_amdgcn_global_load_lds(
        (const __attribute__((address_space(1))) void*)gsrc,
        (__attribute__((address_space(3))) void*)ldst, 16, 0, 0);
}

// ---------------------------------------------------------------------------
// K0: transpose + cast: dst[C][R] (bf16) <- src[R][C] (f32). 64x64 tiles.
// ---------------------------------------------------------------------------
__global__ __launch_bounds__(256) void transp_kernel(
    const float* __restrict__ src, us* __restrict__ dst, int R, int C)
{
    const int c0 = blockIdx.x * 64;
    const int r0 = blockIdx.y * 64;
    const int tid = threadIdx.x;

    __shared__ us T[64][68];

    #pragma unroll
    for (int e = 0; e < 4; e++) {
        int idx = tid + e * 256;
        int jr  = idx >> 4;               // row within tile
        int c4  = (idx & 15) * 4;
        float4 v = *reinterpret_cast<const float4*>(
            src + (size_t)(r0 + jr) * C + c0 + c4);
        us4 w;
        w[0] = f2bfb(v.x); w[1] = f2bfb(v.y); w[2] = f2bfb(v.z); w[3] = f2bfb(v.w);
        *reinterpret_cast<us4*>(&T[jr][c4]) = w;
    }
    __syncthreads();

    #pragma unroll
    for (int e = 0; e < 4; e++) {
        int idx = tid + e * 256;
        int d   = idx >> 4;               // col within tile (dst row)
        int k4  = (idx & 15) * 4;
        us4 w;
        w[0] = T[k4 + 0][d];
        w[1] = T[k4 + 1][d];
        w[2] = T[k4 + 2][d];
        w[3] = T[k4 + 3][d];
        *reinterpret_cast<us4*>(dst + (size_t)(c0 + d) * R + r0 + k4) = w;
    }
}

// ---------------------------------------------------------------------------
// K1: LayerNorm over DIM=2048 -> bf16. One block per token.
// ---------------------------------------------------------------------------
__global__ __launch_bounds__(256) void ln_kernel(
    const float* __restrict__ x, const float* __restrict__ g,
    const float* __restrict__ b, us* __restrict__ xn)
{
    const int t   = blockIdx.x;
    const int tid = threadIdx.x;
    const size_t base = (size_t)t * DIM;

    float4 p0 = reinterpret_cast<const float4*>(x + base)[tid * 2 + 0];
    float4 p1 = reinterpret_cast<const float4*>(x + base)[tid * 2 + 1];
    float v[8] = {p0.x, p0.y, p0.z, p0.w, p1.x, p1.y, p1.z, p1.w};

    float s1 = 0.f, s2 = 0.f;
    #pragma unroll
    for (int i = 0; i < 8; i++) { s1 += v[i]; s2 += v[i] * v[i]; }

    #pragma unroll
    for (int off = 32; off; off >>= 1) {
        s1 += __shfl_xor(s1, off);
        s2 += __shfl_xor(s2, off);
    }
    __shared__ float red1[4], red2[4];
    if ((tid & 63) == 0) { red1[tid >> 6] = s1; red2[tid >> 6] = s2; }
    __syncthreads();
    float S1 = red1[0] + red1[1] + red1[2] + red1[3];
    float S2 = red2[0] + red2[1] + red2[2] + red2[3];
    const float inv = 1.0f / (float)DIM;
    float mu  = S1 * inv;
    float var = S2 * inv - mu * mu;
    float rstd = rsqrtf(var + LN_EPS);

    const int d0 = tid * 8;
    float4 oa, ob;
    oa.x = (v[0] - mu) * rstd * g[d0 + 0] + b[d0 + 0];
    oa.y = (v[1] - mu) * rstd * g[d0 + 1] + b[d0 + 1];
    oa.z = (v[2] - mu) * rstd * g[d0 + 2] + b[d0 + 2];
    oa.w = (v[3] - mu) * rstd * g[d0 + 3] + b[d0 + 3];
    ob.x = (v[4] - mu) * rstd * g[d0 + 4] + b[d0 + 4];
    ob.y = (v[5] - mu) * rstd * g[d0 + 5] + b[d0 + 5];
    ob.z = (v[6] - mu) * rstd * g[d0 + 6] + b[d0 + 6];
    ob.w = (v[7] - mu) * rstd * g[d0 + 7] + b[d0 + 7];

    *reinterpret_cast<us8*>(xn + base + d0) = pack8u(oa, ob);
}

// ---------------------------------------------------------------------------
// K2/K5: MFMA GEMM (B^T layout):  C[M][N] = A[M][K] @ Bt[N][K]^T  (bf16 in)
// m97-template: global_load_lds w=16 into linear [128][32] LDS (64B rows ->
// bank-uniform fragment reads), double-buffered, ONE barrier per K-step.
// ---------------------------------------------------------------------------
template<bool OUT_BF16>
__global__ __launch_bounds__(256) void gemm_bt_kernel(
    const us* __restrict__ A, const us* __restrict__ Bt,
    void* __restrict__ Cout, int M, int N, int K)
{
    __shared__ us As[2][128 * 32];
    __shared__ us Bs[2][128 * 32];

    const int tid  = threadIdx.x;
    const int wave = tid >> 6, lane = tid & 63;
    const int quad = lane >> 4, l16 = lane & 15;
    const int wm = wave & 1, wn = wave >> 1;
    const int m0 = blockIdx.y * 128, n0 = blockIdx.x * 128;

    f32x4 acc[4][4];
    #pragma unroll
    for (int i = 0; i < 4; i++)
        #pragma unroll
        for (int j = 0; j < 4; j++)
            #pragma unroll
            for (int r = 0; r < 4; r++) acc[i][j][r] = 0.f;

    const int s_row = tid >> 2;          // 0..63
    const int s_c8  = (tid & 3) * 8;     // 0,8,16,24

    auto stage = [&](int k0, int buf) {
        #pragma unroll
        for (int e = 0; e < 2; e++) {
            gload_lds16(A  + (size_t)(m0 + e * 64 + s_row) * K + k0 + s_c8,
                        (char*)&As[buf][0] + (e * 256 + tid) * 16);
            gload_lds16(Bt + (size_t)(n0 + e * 64 + s_row) * K + k0 + s_c8,
                        (char*)&Bs[buf][0] + (e * 256 + tid) * 16);
        }
    };

    stage(0, 0);
    __syncthreads();

    int buf = 0;
    for (int k0 = 0; k0 < K; k0 += 32) {
        if (k0 + 32 < K) stage(k0 + 32, buf ^ 1);

        short8 af[4], bf[4];
        #pragma unroll
        for (int mi = 0; mi < 4; mi++)
            af[mi] = *reinterpret_cast<const short8*>(
                &As[buf][(wm * 64 + mi * 16 + l16) * 32 + quad * 8]);
        #pragma unroll
        for (int ni = 0; ni < 4; ni++)
            bf[ni] = *reinterpret_cast<const short8*>(
                &Bs[buf][(wn * 64 + ni * 16 + l16) * 32 + quad * 8]);

        __builtin_amdgcn_s_setprio(1);
        #pragma unroll
        for (int mi = 0; mi < 4; mi++)
            #pragma unroll
            for (int ni = 0; ni < 4; ni++)
                acc[mi][ni] = __builtin_amdgcn_mfma_f32_16x16x32_bf16(
                    af[mi], bf[ni], acc[mi][ni], 0, 0, 0);
        __builtin_amdgcn_s_setprio(0);

        __syncthreads();     // drains vmcnt -> next buffer resident
        buf ^= 1;
    }

    // epilogue: C/D layout col=l16, row=quad*4+r
    #pragma unroll
    for (int mi = 0; mi < 4; mi++) {
        #pragma unroll
        for (int r = 0; r < 4; r++) {
            size_t row = (size_t)(m0 + wm * 64 + mi * 16 + quad * 4 + r);
            #pragma unroll
            for (int ni = 0; ni < 4; ni++) {
                size_t col = n0 + wn * 64 + ni * 16 + l16;
                if (OUT_BF16)
                    ((us*)Cout)[row * N + col] = f2bfb(acc[mi][ni][r]);
                else
                    ((float*)Cout)[row * N + col] = acc[mi][ni][r];
            }
        }
    }
}

// ---------------------------------------------------------------------------
// K3: RoPE + KV cache assembly. qkv is bf16; outputs f32 + bf16 K copy.
// ---------------------------------------------------------------------------
__global__ __launch_bounds__(256) void rope_kernel(
    const float* __restrict__ past_k, const float* __restrict__ past_v,
    us* __restrict__ qkv, float* __restrict__ out_k, float* __restrict__ out_v,
    us* __restrict__ Kbf)
{
    const int tid  = threadIdx.x;
    const int pid  = blockIdx.x * 4 + (tid >> 6);
    const int lane = tid & 63;

    const int b   = pid / (HEADS * KVL);
    const int rem = pid - b * (HEADS * KVL);
    const int h   = rem / KVL;
    const int pos = rem - h * KVL;

    const float invf = exp2f((float)lane * (-13.287712379549449f / 64.0f));
    float sn, cs;
    sincosf((float)pos * invf, &sn, &cs);

    const size_t obase = ((size_t)(b * HEADS + h) * KVL + pos) * DH + 2 * lane;

    float k0, k1;
    if (pos < PAST) {
        const size_t pbase = ((size_t)(b * HEADS + h) * PAST + pos) * DH + 2 * lane;
        k0 = past_k[pbase];
        k1 = past_k[pbase + 1];
    } else {
        const int t = b * NN + (pos - PAST);
        const us* qp = qkv + (size_t)t * NQKV + INNER + h * DH + 2 * lane;
        k0 = bfbits2f(qp[0]); k1 = bfbits2f(qp[1]);
    }
    float kr0 = k0 * cs - k1 * sn;
    float kr1 = k1 * cs + k0 * sn;
    out_k[obase]     = kr0;
    out_k[obase + 1] = kr1;
    Kbf[obase]       = f2bfb(kr0);
    Kbf[obase + 1]   = f2bfb(kr1);

    if (pos < PAST) {
        const size_t pbase = ((size_t)(b * HEADS + h) * PAST + pos) * DH + 2 * lane;
        out_v[obase]     = past_v[pbase];
        out_v[obase + 1] = past_v[pbase + 1];
    } else {
        const int t = b * NN + (pos - PAST);
        const us* vp = qkv + (size_t)t * NQKV + 2 * INNER + h * DH + 2 * lane;
        out_v[obase]     = bfbits2f(vp[0]);
        out_v[obase + 1] = bfbits2f(vp[1]);
    }

    if (pos >= PAST) {
        const int t = b * NN + (pos - PAST);
        us* qq = qkv + (size_t)t * NQKV + h * DH + 2 * lane;
        float q0 = bfbits2f(qq[0]), q1 = bfbits2f(qq[1]);
        qq[0] = f2bfb(q0 * cs - q1 * sn);
        qq[1] = f2bfb(q1 * cs + q0 * sn);
    }
}

// ---------------------------------------------------------------------------
// K3b: V transpose to bf16: Vtg[bh][d][kv] <- bf16(out_v[bh][kv][d])
// ---------------------------------------------------------------------------
__global__ __launch_bounds__(256) void vtrans_kernel(
    const float* __restrict__ Vc, us* __restrict__ Vtg)
{
    const int jb = blockIdx.x;
    const int db = blockIdx.y;
    const int bh = blockIdx.z;
    const int tid = threadIdx.x;

    __shared__ us T[64][68];

    const float* src = Vc + ((size_t)bh * KVL + jb * 64) * DH + db * 64;
    #pragma unroll
    for (int e = 0; e < 4; e++) {
        int idx = tid + e * 256;
        int jr  = idx >> 4;
        int c4  = (idx & 15) * 4;
        float4 v = *reinterpret_cast<const float4*>(src + (size_t)jr * DH + c4);
        us4 w;
        w[0] = f2bfb(v.x); w[1] = f2bfb(v.y); w[2] = f2bfb(v.z); w[3] = f2bfb(v.w);
        *reinterpret_cast<us4*>(&T[jr][c4]) = w;
    }
    __syncthreads();

    us* dst = Vtg + ((size_t)bh * DH + db * 64) * KVL + jb * 64;
    #pragma unroll
    for (int e = 0; e < 4; e++) {
        int idx = tid + e * 256;
        int d   = idx >> 4;
        int k4  = (idx & 15) * 4;
        us4 w;
        w[0] = T[k4 + 0][d];
        w[1] = T[k4 + 1][d];
        w[2] = T[k4 + 2][d];
        w[3] = T[k4 + 3][d];
        *reinterpret_cast<us4*>(dst + (size_t)d * KVL + k4) = w;
    }
}

// ---------------------------------------------------------------------------
// K4: MFMA flash attention, swapped-QK^T form.
// S = mfma(K, Q): lane owns one q-row (q = l16) x 16 k-values -> in-lane
// row-max tree + 2 shfl (was 8 serial shfl x 4 rows). Partial row-sum kept
// per (l16,quad), reduced cross-quad ONCE at the end. Defer-max (THR=8)
// skips the O-rescale on most chunks. Mid-chunk barrier removed (Pb is
// wave-private) -> one __syncthreads per chunk.
// ---------------------------------------------------------------------------
__global__ __launch_bounds__(256) void attn_mfma_kernel(
    const us* __restrict__ qkv,               // [TOK][NQKV] bf16, q roped
    const us* __restrict__ Kbf,               // [bh][KVL][DH] bf16 (roped)
    const us* __restrict__ Vtg,               // [bh][DH][KVL] bf16
    us* __restrict__ Ao)                      // [TOK][INNER] bf16
{
    const int qt   = blockIdx.x;
    const int h    = blockIdx.y;
    const int b    = blockIdx.z;
    const int tid  = threadIdx.x;
    const int wave = tid >> 6;
    const int lane = tid & 63;
    const int quad = lane >> 4;
    const int l16  = lane & 15;

    __shared__ us Ks[2][64 * 128];   // 16 KB x2, swizzled rows of 256 B
    __shared__ us Vt[2][128 * 64];   // 16 KB x2, swizzled rows of 128 B
    __shared__ us Pb[64][72];        // 9 KB, per-wave 16-row slabs
    __shared__ float alF[4][16];     // per-wave alpha broadcast

    // Q B-fragments (rows = q = wave*16 + l16)
    short8 qf[4];
    {
        const int qrow = qt * 64 + wave * 16 + l16;
        const us* qp = qkv + (size_t)(b * NN + qrow) * NQKV + h * DH;
        #pragma unroll
        for (int ks = 0; ks < 4; ks++)
            qf[ks] = *reinterpret_cast<const short8*>(qp + ks * 32 + quad * 8);
    }

    f32x4 Oacc[8];
    #pragma unroll
    for (int t = 0; t < 8; t++)
        #pragma unroll
        for (int r = 0; r < 4; r++) Oacc[t][r] = 0.f;
    float m_run  = -INFINITY;   // running max for q = l16 (unscaled S units)
    float l_part = 0.f;         // partial denom for q = l16 over this quad's k

    const us* kptr = Kbf + (size_t)(b * HEADS + h) * KVL * DH;
    const us* vtb  = Vtg + (size_t)(b * HEADS + h) * DH * KVL;
    const float scale = 0.08838834764831845f;
    const float THRU  = 90.50966799f;          // 8 / scale
    const int qg  = PAST + qt * 64 + wave * 16 + l16;   // global q pos
    const int nch = 17 + qt;

    auto stage = [&](int j0, int buf) {
        // K chunk: 64 rows x 256 B, XOR-swizzled via pre-swizzled global src
        #pragma unroll
        for (int e = 0; e < 4; e++) {
            int phys = (e * 256 + tid) * 16;
            int row  = phys >> 8;
            int col  = (phys & 255) ^ ((row & 7) << 4);
            gload_lds16((const char*)(kptr + (size_t)(j0 + row) * DH) + col,
                        (char*)&Ks[buf][0] + phys);
        }
        // V chunk: 128 rows x 128 B
        #pragma unroll
        for (int e = 0; e < 4; e++) {
            int phys = (e * 256 + tid) * 16;
            int row  = phys >> 7;
            int col  = (phys & 127) ^ ((row & 7) << 4);
            gload_lds16((const char*)(vtb + (size_t)row * KVL + j0) + col,
                        (char*)&Vt[buf][0] + phys);
        }
    };

    stage(0, 0);
    __syncthreads();            // drains vmcnt -> chunk 0 resident

    int cur = 0;
    for (int c = 0; c < nch; c++) {
        const int j0 = c * 64;
        if (c + 1 < nch) stage(j0 + 64, cur ^ 1);   // async prefetch

        // ---- QK^T (swapped: A=K rows=k, B=Q rows=q) ----
        // S[t] row = k = quad*4+r (within t*16 tile), col = q = l16
        f32x4 S[4];
        #pragma unroll
        for (int t = 0; t < 4; t++)
            #pragma unroll
            for (int r = 0; r < 4; r++) S[t][r] = 0.f;
        __builtin_amdgcn_s_setprio(1);
        #pragma unroll
        for (int ks = 0; ks < 4; ks++) {
            #pragma unroll
            for (int t = 0; t < 4; t++) {
                int row  = t * 16 + l16;
                int colb = ks * 64 + quad * 16;
                const char* p = (const char*)&Ks[cur][0] +
                                row * 256 + (colb ^ ((row & 7) << 4));
                short8 kb = *reinterpret_cast<const short8*>(p);
                S[t] = __builtin_amdgcn_mfma_f32_16x16x32_bf16(kb, qf[ks], S[t], 0, 0, 0);
            }
        }
        __builtin_amdgcn_s_setprio(0);

        // ---- mask + in-lane row max ----
        const int rel = qg - j0;        // valid iff koff <= rel
        float mx = -INFINITY;
        #pragma unroll
        for (int t = 0; t < 4; t++) {
            #pragma unroll
            for (int r = 0; r < 4; r++) {
                int koff = t * 16 + quad * 4 + r;
                S[t][r] = (koff <= rel) ? S[t][r] : -INFINITY;
                mx = fmaxf(mx, S[t][r]);
            }
        }
        mx = fmaxf(mx, __shfl_xor(mx, 16));
        mx = fmaxf(mx, __shfl_xor(mx, 32));

        // ---- defer-max: rescale only when the max actually grew ----
        float alpha = 1.f;
        if (__any(mx > m_run + THRU)) {
            float nm = fmaxf(m_run, mx);
            alpha = __expf((m_run - nm) * scale);
            m_run = nm;
            if (quad == 0) alF[wave][l16] = alpha;
            asm volatile("s_waitcnt lgkmcnt(0)" ::: "memory");
            float a0 = alF[wave][quad * 4 + 0];
            float a1 = alF[wave][quad * 4 + 1];
            float a2 = alF[wave][quad * 4 + 2];
            float a3 = alF[wave][quad * 4 + 3];
            #pragma unroll
            for (int t2 = 0; t2 < 8; t2++) {
                Oacc[t2][0] *= a0; Oacc[t2][1] *= a1;
                Oacc[t2][2] *= a2; Oacc[t2][3] *= a3;
            }
        }

        // ---- P = exp(S*scale - m*scale), partial sum, pack to LDS ----
        const float nmk = -m_run * scale;
        float rs = 0.f;
        #pragma unroll
        for (int t = 0; t < 4; t++) {
            us4 w;
            #pragma unroll
            for (int r = 0; r < 4; r++) {
                float p = __expf(fmaf(S[t][r], scale, nmk));  // masked -> 0
                rs += p;
                w[r] = f2bfb(p);
            }
            *reinterpret_cast<us4*>(&Pb[wave * 16 + l16][t * 16 + quad * 4]) = w;
        }
        l_part = l_part * alpha + rs;

        // Pb is wave-private: LDS-only drain, NO barrier, loads stay in flight
        asm volatile("s_waitcnt lgkmcnt(0)" ::: "memory");
        __builtin_amdgcn_sched_barrier(0);

        // ---- PV ----
        __builtin_amdgcn_s_setprio(1);
        #pragma unroll
        for (int kh = 0; kh < 2; kh++) {
            short8 pa = *reinterpret_cast<const short8*>(
                &Pb[wave * 16 + l16][kh * 32 + quad * 8]);
            #pragma unroll
            for (int t2 = 0; t2 < 8; t2++) {
                int row  = t2 * 16 + l16;
                int colb = kh * 64 + quad * 16;
                const char* p = (const char*)&Vt[cur][0] +
                                row * 128 + (colb ^ ((row & 7) << 4));
                short8 vb = *reinterpret_cast<const short8*>(p);
                Oacc[t2] = __builtin_amdgcn_mfma_f32_16x16x32_bf16(pa, vb, Oacc[t2], 0, 0, 0);
            }
        }
        __builtin_amdgcn_s_setprio(0);

        __syncthreads();        // full drain: prefetch landed, Vt/Ks swap safe
        cur ^= 1;
    }

    // final denom: cross-quad reduce, then redistribute to q = quad*4+r lanes
    l_part += __shfl_xor(l_part, 16);
    l_part += __shfl_xor(l_part, 32);
    float invl[4];
    #pragma unroll
    for (int r = 0; r < 4; r++)
        invl[r] = 1.f / __shfl(l_part, quad * 4 + r);

    const int row0 = b * NN + qt * 64 + wave * 16 + quad * 4;
    #pragma unroll
    for (int r = 0; r < 4; r++) {
        us* dst = Ao + (size_t)(row0 + r) * INNER + h * DH + l16;
        #pragma unroll
        for (int t2 = 0; t2 < 8; t2++)
            dst[t2 * 16] = f2bfb(Oacc[t2][r] * invl[r]);
    }
}

// ---------------------------------------------------------------------------
extern "C" void kernel_launch(void* const* d_in, const int* in_sizes, int n_in,
                              void* d_out, int out_size, void* d_ws, size_t ws_size,
                              hipStream_t stream)
{
    const float* x      = (const float*)d_in[0];
    const float* past_k = (const float*)d_in[1];
    const float* past_v = (const float*)d_in[2];
    // d_in[3] = mask (unused; computed analytically)
    const float* w_qkv  = (const float*)d_in[4];
    const float* w_out  = (const float*)d_in[5];
    const float* ln_g   = (const float*)d_in[6];
    const float* ln_b   = (const float*)d_in[7];

    float* out   = (float*)d_out;                      // [B,N,DIM]
    float* out_k = out   + (size_t)BB * NN * DIM;      // [B,H,KVL,DH]
    float* out_v = out_k + (size_t)BB * HEADS * KVL * DH;

    // ws (bf16 buffers), 80 MB total:
    us* xn   = (us*)d_ws;                              // [TOK][DIM]     8 MB
    us* qkv  = xn  + (size_t)TOK * DIM;                // [TOK][NQKV]   24 MB
    us* Wqt  = qkv + (size_t)TOK * NQKV;               // [NQKV][DIM]   24 MB
    us* Wot  = Wqt + (size_t)NQKV * DIM;               // [DIM][INNER]   8 MB
    us* Vtg  = Wot + (size_t)DIM * INNER;              // [bh][DH][KVL] 16 MB
    us* attn = xn;   // alias: xn dead after qkv GEMM  // [TOK][INNER]   8 MB
    us* Kbf  = Wqt;  // alias: Wqt dead after qkv GEMM // [bh][KVL][DH] 16.7 MB

    transp_kernel<<<dim3(NQKV / 64, DIM / 64), 256, 0, stream>>>(
        w_qkv, Wqt, DIM, NQKV);
    transp_kernel<<<dim3(DIM / 64, INNER / 64), 256, 0, stream>>>(
        w_out, Wot, INNER, DIM);

    ln_kernel<<<TOK, 256, 0, stream>>>(x, ln_g, ln_b, xn);

    gemm_bt_kernel<true><<<dim3(NQKV / 128, TOK / 128), 256, 0, stream>>>(
        xn, Wqt, (void*)qkv, TOK, NQKV, DIM);

    rope_kernel<<<(BB * HEADS * KVL) / 4, 256, 0, stream>>>(
        past_k, past_v, qkv, out_k, out_v, Kbf);

    vtrans_kernel<<<dim3(KVL / 64, DH / 64, BB * HEADS), 256, 0, stream>>>(
        out_v, Vtg);

    attn_mfma_kernel<<<dim3(NN / 64, HEADS, BB), 256, 0, stream>>>(
        qkv, Kbf, Vtg, attn);

    gemm_bt_kernel<false><<<dim3(DIM / 128, TOK / 128), 256, 0, stream>>>(
        attn, Wot, (void*)out, TOK, DIM, INNER);
}

// Round 3
// 378.670 us; speedup vs baseline: 1.2616x; 1.0069x over previous
//
#include <hip/hip_runtime.h>
#include <hip/hip_bf16.h>
#include <math.h>

// Problem constants
#define BB    2
#define NN    1024
#define PAST  1024
#define KVL   2048            // PAST + NN
#define DIM   2048
#define HEADS 16
#define DH    128
#define INNER 2048            // HEADS*DH
#define NQKV  6144            // 3*INNER
#define TOK   2048            // BB*NN
#define LN_EPS 1e-5f

typedef __attribute__((ext_vector_type(8))) short   short8;   // 8 bf16 (4 VGPR)
typedef __attribute__((ext_vector_type(4))) float   f32x4;
typedef __attribute__((ext_vector_type(8))) unsigned short us8;
typedef __attribute__((ext_vector_type(4))) unsigned short us4;
typedef unsigned short us;

__device__ __forceinline__ float bfbits2f(us u) {
    return __uint_as_float(((unsigned int)u) << 16);
}
__device__ __forceinline__ us f2bfb(float f) {
    union { __hip_bfloat16 h; us u; } cv;
    cv.h = __float2bfloat16(f);           // RNE
    return cv.u;
}
__device__ __forceinline__ us8 pack8u(float4 a, float4 b) {
    us8 r;
    r[0] = f2bfb(a.x); r[1] = f2bfb(a.y); r[2] = f2bfb(a.z); r[3] = f2bfb(a.w);
    r[4] = f2bfb(b.x); r[5] = f2bfb(b.y); r[6] = f2bfb(b.z); r[7] = f2bfb(b.w);
    return r;
}

// async global->LDS, 16B per lane. LDS dest must be linear (base + lane*16);
// swizzled layouts are achieved by pre-swizzling the GLOBAL source address.
__device__ __forceinline__ void gload_lds16(const void* gsrc, void* ldst) {
    __builtin_amdgcn_global_load_lds(
        (const __attribute__((address_space(1))) void*)gsrc,
        (__attribute__((address_space(3))) void*)ldst, 16, 0, 0);
}

// ---------------------------------------------------------------------------
// K0: transpose + cast: dst[C][R] (bf16) <- src[R][C] (f32). 64x64 tiles.
// ---------------------------------------------------------------------------
__global__ __launch_bounds__(256) void transp_kernel(
    const float* __restrict__ src, us* __restrict__ dst, int R, int C)
{
    const int c0 = blockIdx.x * 64;
    const int r0 = blockIdx.y * 64;
    const int tid = threadIdx.x;

    __shared__ us T[64][68];

    #pragma unroll
    for (int e = 0; e < 4; e++) {
        int idx = tid + e * 256;
        int jr  = idx >> 4;               // row within tile
        int c4  = (idx & 15) * 4;
        float4 v = *reinterpret_cast<const float4*>(
            src + (size_t)(r0 + jr) * C + c0 + c4);
        us4 w;
        w[0] = f2bfb(v.x); w[1] = f2bfb(v.y); w[2] = f2bfb(v.z); w[3] = f2bfb(v.w);
        *reinterpret_cast<us4*>(&T[jr][c4]) = w;
    }
    __syncthreads();

    #pragma unroll
    for (int e = 0; e < 4; e++) {
        int idx = tid + e * 256;
        int d   = idx >> 4;               // col within tile (dst row)
        int k4  = (idx & 15) * 4;
        us4 w;
        w[0] = T[k4 + 0][d];
        w[1] = T[k4 + 1][d];
        w[2] = T[k4 + 2][d];
        w[3] = T[k4 + 3][d];
        *reinterpret_cast<us4*>(dst + (size_t)(c0 + d) * R + r0 + k4) = w;
    }
}

// ---------------------------------------------------------------------------
// K1: LayerNorm over DIM=2048 -> bf16. One block per token.
// ---------------------------------------------------------------------------
__global__ __launch_bounds__(256) void ln_kernel(
    const float* __restrict__ x, const float* __restrict__ g,
    const float* __restrict__ b, us* __restrict__ xn)
{
    const int t   = blockIdx.x;
    const int tid = threadIdx.x;
    const size_t base = (size_t)t * DIM;

    float4 p0 = reinterpret_cast<const float4*>(x + base)[tid * 2 + 0];
    float4 p1 = reinterpret_cast<const float4*>(x + base)[tid * 2 + 1];
    float v[8] = {p0.x, p0.y, p0.z, p0.w, p1.x, p1.y, p1.z, p1.w};

    float s1 = 0.f, s2 = 0.f;
    #pragma unroll
    for (int i = 0; i < 8; i++) { s1 += v[i]; s2 += v[i] * v[i]; }

    #pragma unroll
    for (int off = 32; off; off >>= 1) {
        s1 += __shfl_xor(s1, off);
        s2 += __shfl_xor(s2, off);
    }
    __shared__ float red1[4], red2[4];
    if ((tid & 63) == 0) { red1[tid >> 6] = s1; red2[tid >> 6] = s2; }
    __syncthreads();
    float S1 = red1[0] + red1[1] + red1[2] + red1[3];
    float S2 = red2[0] + red2[1] + red2[2] + red2[3];
    const float inv = 1.0f / (float)DIM;
    float mu  = S1 * inv;
    float var = S2 * inv - mu * mu;
    float rstd = rsqrtf(var + LN_EPS);

    const int d0 = tid * 8;
    float4 oa, ob;
    oa.x = (v[0] - mu) * rstd * g[d0 + 0] + b[d0 + 0];
    oa.y = (v[1] - mu) * rstd * g[d0 + 1] + b[d0 + 1];
    oa.z = (v[2] - mu) * rstd * g[d0 + 2] + b[d0 + 2];
    oa.w = (v[3] - mu) * rstd * g[d0 + 3] + b[d0 + 3];
    ob.x = (v[4] - mu) * rstd * g[d0 + 4] + b[d0 + 4];
    ob.y = (v[5] - mu) * rstd * g[d0 + 5] + b[d0 + 5];
    ob.z = (v[6] - mu) * rstd * g[d0 + 6] + b[d0 + 6];
    ob.w = (v[7] - mu) * rstd * g[d0 + 7] + b[d0 + 7];

    *reinterpret_cast<us8*>(xn + base + d0) = pack8u(oa, ob);
}

// ---------------------------------------------------------------------------
// K2/K5: MFMA GEMM (B^T layout):  C[M][N] = A[M][K] @ Bt[N][K]^T  (bf16 in)
// m97-template: global_load_lds w=16 into linear [128][32] LDS (64B rows ->
// bank-uniform fragment reads), double-buffered, ONE barrier per K-step.
// ---------------------------------------------------------------------------
template<bool OUT_BF16>
__global__ __launch_bounds__(256) void gemm_bt_kernel(
    const us* __restrict__ A, const us* __restrict__ Bt,
    void* __restrict__ Cout, int M, int N, int K)
{
    __shared__ us As[2][128 * 32];
    __shared__ us Bs[2][128 * 32];

    const int tid  = threadIdx.x;
    const int wave = tid >> 6, lane = tid & 63;
    const int quad = lane >> 4, l16 = lane & 15;
    const int wm = wave & 1, wn = wave >> 1;
    const int m0 = blockIdx.y * 128, n0 = blockIdx.x * 128;

    f32x4 acc[4][4];
    #pragma unroll
    for (int i = 0; i < 4; i++)
        #pragma unroll
        for (int j = 0; j < 4; j++)
            #pragma unroll
            for (int r = 0; r < 4; r++) acc[i][j][r] = 0.f;

    const int s_row = tid >> 2;          // 0..63
    const int s_c8  = (tid & 3) * 8;     // 0,8,16,24

    auto stage = [&](int k0, int buf) {
        #pragma unroll
        for (int e = 0; e < 2; e++) {
            gload_lds16(A  + (size_t)(m0 + e * 64 + s_row) * K + k0 + s_c8,
                        (char*)&As[buf][0] + (e * 256 + tid) * 16);
            gload_lds16(Bt + (size_t)(n0 + e * 64 + s_row) * K + k0 + s_c8,
                        (char*)&Bs[buf][0] + (e * 256 + tid) * 16);
        }
    };

    stage(0, 0);
    __syncthreads();

    int buf = 0;
    for (int k0 = 0; k0 < K; k0 += 32) {
        if (k0 + 32 < K) stage(k0 + 32, buf ^ 1);

        short8 af[4], bf[4];
        #pragma unroll
        for (int mi = 0; mi < 4; mi++)
            af[mi] = *reinterpret_cast<const short8*>(
                &As[buf][(wm * 64 + mi * 16 + l16) * 32 + quad * 8]);
        #pragma unroll
        for (int ni = 0; ni < 4; ni++)
            bf[ni] = *reinterpret_cast<const short8*>(
                &Bs[buf][(wn * 64 + ni * 16 + l16) * 32 + quad * 8]);

        __builtin_amdgcn_s_setprio(1);
        #pragma unroll
        for (int mi = 0; mi < 4; mi++)
            #pragma unroll
            for (int ni = 0; ni < 4; ni++)
                acc[mi][ni] = __builtin_amdgcn_mfma_f32_16x16x32_bf16(
                    af[mi], bf[ni], acc[mi][ni], 0, 0, 0);
        __builtin_amdgcn_s_setprio(0);

        __syncthreads();     // drains vmcnt -> next buffer resident
        buf ^= 1;
    }

    // epilogue: C/D layout col=l16, row=quad*4+r
    #pragma unroll
    for (int mi = 0; mi < 4; mi++) {
        #pragma unroll
        for (int r = 0; r < 4; r++) {
            size_t row = (size_t)(m0 + wm * 64 + mi * 16 + quad * 4 + r);
            #pragma unroll
            for (int ni = 0; ni < 4; ni++) {
                size_t col = n0 + wn * 64 + ni * 16 + l16;
                if (OUT_BF16)
                    ((us*)Cout)[row * N + col] = f2bfb(acc[mi][ni][r]);
                else
                    ((float*)Cout)[row * N + col] = acc[mi][ni][r];
            }
        }
    }
}

// ---------------------------------------------------------------------------
// K3: RoPE + KV cache assembly. qkv is bf16; outputs f32 + bf16 K copy.
// ---------------------------------------------------------------------------
__global__ __launch_bounds__(256) void rope_kernel(
    const float* __restrict__ past_k, const float* __restrict__ past_v,
    us* __restrict__ qkv, float* __restrict__ out_k, float* __restrict__ out_v,
    us* __restrict__ Kbf)
{
    const int tid  = threadIdx.x;
    const int pid  = blockIdx.x * 4 + (tid >> 6);
    const int lane = tid & 63;

    const int b   = pid / (HEADS * KVL);
    const int rem = pid - b * (HEADS * KVL);
    const int h   = rem / KVL;
    const int pos = rem - h * KVL;

    const float invf = exp2f((float)lane * (-13.287712379549449f / 64.0f));
    float sn, cs;
    sincosf((float)pos * invf, &sn, &cs);

    const size_t obase = ((size_t)(b * HEADS + h) * KVL + pos) * DH + 2 * lane;

    float k0, k1;
    if (pos < PAST) {
        const size_t pbase = ((size_t)(b * HEADS + h) * PAST + pos) * DH + 2 * lane;
        k0 = past_k[pbase];
        k1 = past_k[pbase + 1];
    } else {
        const int t = b * NN + (pos - PAST);
        const us* qp = qkv + (size_t)t * NQKV + INNER + h * DH + 2 * lane;
        k0 = bfbits2f(qp[0]); k1 = bfbits2f(qp[1]);
    }
    float kr0 = k0 * cs - k1 * sn;
    float kr1 = k1 * cs + k0 * sn;
    out_k[obase]     = kr0;
    out_k[obase + 1] = kr1;
    Kbf[obase]       = f2bfb(kr0);
    Kbf[obase + 1]   = f2bfb(kr1);

    if (pos < PAST) {
        const size_t pbase = ((size_t)(b * HEADS + h) * PAST + pos) * DH + 2 * lane;
        out_v[obase]     = past_v[pbase];
        out_v[obase + 1] = past_v[pbase + 1];
    } else {
        const int t = b * NN + (pos - PAST);
        const us* vp = qkv + (size_t)t * NQKV + 2 * INNER + h * DH + 2 * lane;
        out_v[obase]     = bfbits2f(vp[0]);
        out_v[obase + 1] = bfbits2f(vp[1]);
    }

    if (pos >= PAST) {
        const int t = b * NN + (pos - PAST);
        us* qq = qkv + (size_t)t * NQKV + h * DH + 2 * lane;
        float q0 = bfbits2f(qq[0]), q1 = bfbits2f(qq[1]);
        qq[0] = f2bfb(q0 * cs - q1 * sn);
        qq[1] = f2bfb(q1 * cs + q0 * sn);
    }
}

// ---------------------------------------------------------------------------
// K3b: V transpose to bf16: Vtg[bh][d][kv] <- bf16(out_v[bh][kv][d])
// ---------------------------------------------------------------------------
__global__ __launch_bounds__(256) void vtrans_kernel(
    const float* __restrict__ Vc, us* __restrict__ Vtg)
{
    const int jb = blockIdx.x;
    const int db = blockIdx.y;
    const int bh = blockIdx.z;
    const int tid = threadIdx.x;

    __shared__ us T[64][68];

    const float* src = Vc + ((size_t)bh * KVL + jb * 64) * DH + db * 64;
    #pragma unroll
    for (int e = 0; e < 4; e++) {
        int idx = tid + e * 256;
        int jr  = idx >> 4;
        int c4  = (idx & 15) * 4;
        float4 v = *reinterpret_cast<const float4*>(src + (size_t)jr * DH + c4);
        us4 w;
        w[0] = f2bfb(v.x); w[1] = f2bfb(v.y); w[2] = f2bfb(v.z); w[3] = f2bfb(v.w);
        *reinterpret_cast<us4*>(&T[jr][c4]) = w;
    }
    __syncthreads();

    us* dst = Vtg + ((size_t)bh * DH + db * 64) * KVL + jb * 64;
    #pragma unroll
    for (int e = 0; e < 4; e++) {
        int idx = tid + e * 256;
        int d   = idx >> 4;
        int k4  = (idx & 15) * 4;
        us4 w;
        w[0] = T[k4 + 0][d];
        w[1] = T[k4 + 1][d];
        w[2] = T[k4 + 2][d];
        w[3] = T[k4 + 3][d];
        *reinterpret_cast<us4*>(dst + (size_t)d * KVL + k4) = w;
    }
}

// ---------------------------------------------------------------------------
// K4: MFMA flash attention, paired-tile + XCD-local form.
// 512 threads / 8 waves per block. Waves 0-3 handle q-tile p, waves 4-7
// handle q-tile 15-p -> per-block compute is EXACTLY 49 tile-chunks
// (uniform), and each staged K/V chunk feeds both tiles (staging x0.58).
// Block decode puts the 16 qt-blocks sharing (b,h) K/V on ONE XCD
// (4 groups x 8 pairs per XCD = 4 MB K/V = its L2).
// ---------------------------------------------------------------------------
__global__ __launch_bounds__(512) void attn_mfma_kernel(
    const us* __restrict__ qkv,               // [TOK][NQKV] bf16, q roped
    const us* __restrict__ Kbf,               // [bh][KVL][DH] bf16 (roped)
    const us* __restrict__ Vtg,               // [bh][DH][KVL] bf16
    us* __restrict__ Ao)                      // [TOK][INNER] bf16
{
    const int tid  = threadIdx.x;
    const int wave = tid >> 6;
    const int lane = tid & 63;
    const int quad = lane >> 4;
    const int l16  = lane & 15;

    // XCD-aware decode: blk%8 -> XCD (HW round-robin); each XCD gets
    // 4 (b,h) groups x 8 pairs = 32 blocks on its 32 CUs.
    const int flat = blockIdx.x;
    const int s    = flat >> 3;               // 0..31
    const int g    = (flat & 7) + 8 * (s & 3);// group = h + 16*b, 0..31
    const int p    = s >> 2;                  // pair 0..7
    const int h    = g & 15;
    const int b    = g >> 4;
    const int qtile = (wave < 4) ? p : (15 - p);
    const int nch   = 32 - p;                 // tile-B chunk count (loop bound)
    const int mynch = (wave < 4) ? (17 + p) : (32 - p);

    __shared__ us Ks[2][64 * 128];   // 16 KB x2, swizzled rows of 256 B
    __shared__ us Vt[2][128 * 64];   // 16 KB x2, swizzled rows of 128 B
    __shared__ us Pb[8][16 * 64];    // 2 KB per wave, swizzled rows of 128 B

    // Q B-fragments (rows = q = qtile*64 + (wave&3)*16 + l16)
    short8 qf[4];
    {
        const int qrow = qtile * 64 + (wave & 3) * 16 + l16;
        const us* qp = qkv + (size_t)(b * NN + qrow) * NQKV + h * DH;
        #pragma unroll
        for (int ks = 0; ks < 4; ks++)
            qf[ks] = *reinterpret_cast<const short8*>(qp + ks * 32 + quad * 8);
    }

    f32x4 Oacc[8];
    #pragma unroll
    for (int t = 0; t < 8; t++)
        #pragma unroll
        for (int r = 0; r < 4; r++) Oacc[t][r] = 0.f;
    float m_run  = -INFINITY;   // running max for q = l16 (unscaled S units)
    float l_part = 0.f;         // partial denom for q = l16 over this quad's k

    const us* kptr = Kbf + (size_t)(b * HEADS + h) * KVL * DH;
    const us* vtb  = Vtg + (size_t)(b * HEADS + h) * DH * KVL;
    const float scale = 0.08838834764831845f;
    const float THRU  = 90.50966799f;          // 8 / scale
    const int qg  = PAST + qtile * 64 + (wave & 3) * 16 + l16;
    const int swz = (l16 & 7) << 4;
    char* pbb = (char*)&Pb[wave][0];

    auto stage = [&](int j0, int buf) {
        // K chunk: 64 rows x 256 B, XOR-swizzled via pre-swizzled global src
        #pragma unroll
        for (int e = 0; e < 2; e++) {
            int phys = (e * 512 + tid) * 16;
            int row  = phys >> 8;
            int col  = (phys & 255) ^ ((row & 7) << 4);
            gload_lds16((const char*)(kptr + (size_t)(j0 + row) * DH) + col,
                        (char*)&Ks[buf][0] + phys);
        }
        // V chunk: 128 rows x 128 B
        #pragma unroll
        for (int e = 0; e < 2; e++) {
            int phys = (e * 512 + tid) * 16;
            int row  = phys >> 7;
            int col  = (phys & 127) ^ ((row & 7) << 4);
            gload_lds16((const char*)(vtb + (size_t)row * KVL) + j0 * 2 + col,
                        (char*)&Vt[buf][0] + phys);
        }
    };

    stage(0, 0);
    __syncthreads();            // drains vmcnt -> chunk 0 resident

    int cur = 0;
    for (int c = 0; c < nch; c++) {
        const int j0 = c * 64;
        if (c + 1 < nch) stage(j0 + 64, cur ^ 1);   // async prefetch

        if (c < mynch) {
            // ---- QK^T (swapped: A=K rows=k, B=Q rows=q) ----
            f32x4 S[4];
            #pragma unroll
            for (int t = 0; t < 4; t++)
                #pragma unroll
                for (int r = 0; r < 4; r++) S[t][r] = 0.f;
            __builtin_amdgcn_s_setprio(1);
            #pragma unroll
            for (int ks = 0; ks < 4; ks++) {
                #pragma unroll
                for (int t = 0; t < 4; t++) {
                    int row  = t * 16 + l16;
                    int colb = ks * 64 + quad * 16;
                    const char* kp = (const char*)&Ks[cur][0] +
                                    row * 256 + (colb ^ ((row & 7) << 4));
                    short8 kb = *reinterpret_cast<const short8*>(kp);
                    S[t] = __builtin_amdgcn_mfma_f32_16x16x32_bf16(kb, qf[ks], S[t], 0, 0, 0);
                }
            }
            __builtin_amdgcn_s_setprio(0);

            // ---- mask + in-lane row max ----
            const int rel = qg - j0;        // valid iff koff <= rel
            float mx = -INFINITY;
            #pragma unroll
            for (int t = 0; t < 4; t++) {
                #pragma unroll
                for (int r = 0; r < 4; r++) {
                    int koff = t * 16 + quad * 4 + r;
                    S[t][r] = (koff <= rel) ? S[t][r] : -INFINITY;
                    mx = fmaxf(mx, S[t][r]);
                }
            }
            mx = fmaxf(mx, __shfl_xor(mx, 16));
            mx = fmaxf(mx, __shfl_xor(mx, 32));

            // ---- defer-max: rescale only when the max actually grew ----
            float alpha = 1.f;
            if (__any(mx > m_run + THRU)) {
                float nm = fmaxf(m_run, mx);
                alpha = __expf((m_run - nm) * scale);
                m_run = nm;
                float al[4];
                #pragma unroll
                for (int r = 0; r < 4; r++) al[r] = __shfl(alpha, quad * 4 + r);
                #pragma unroll
                for (int t2 = 0; t2 < 8; t2++) {
                    Oacc[t2][0] *= al[0]; Oacc[t2][1] *= al[1];
                    Oacc[t2][2] *= al[2]; Oacc[t2][3] *= al[3];
                }
            }

            // ---- P = exp(S*scale - m*scale), partial sum, pack to LDS ----
            const float nmk = -m_run * scale;
            float rs = 0.f;
            #pragma unroll
            for (int t = 0; t < 4; t++) {
                us4 w;
                #pragma unroll
                for (int r = 0; r < 4; r++) {
                    float pv = __expf(fmaf(S[t][r], scale, nmk));  // masked -> 0
                    rs += pv;
                    w[r] = f2bfb(pv);
                }
                *reinterpret_cast<us4*>(pbb + l16 * 128 +
                                        ((t * 32 + quad * 8) ^ swz)) = w;
            }
            l_part = l_part * alpha + rs;

            // Pb is wave-private: LDS-only drain, NO barrier
            asm volatile("s_waitcnt lgkmcnt(0)" ::: "memory");
            __builtin_amdgcn_sched_barrier(0);

            // ---- PV ----
            __builtin_amdgcn_s_setprio(1);
            #pragma unroll
            for (int kh = 0; kh < 2; kh++) {
                short8 pa = *reinterpret_cast<const short8*>(
                    pbb + l16 * 128 + ((kh * 64 + quad * 16) ^ swz));
                #pragma unroll
                for (int t2 = 0; t2 < 8; t2++) {
                    int row  = t2 * 16 + l16;
                    int colb = kh * 64 + quad * 16;
                    const char* vp = (const char*)&Vt[cur][0] +
                                    row * 128 + (colb ^ ((row & 7) << 4));
                    short8 vb = *reinterpret_cast<const short8*>(vp);
                    Oacc[t2] = __builtin_amdgcn_mfma_f32_16x16x32_bf16(pa, vb, Oacc[t2], 0, 0, 0);
                }
            }
            __builtin_amdgcn_s_setprio(0);
        }

        __syncthreads();        // full drain: prefetch landed, Vt/Ks swap safe
        cur ^= 1;
    }

    // final denom: cross-quad reduce, then redistribute to q = quad*4+r lanes
    l_part += __shfl_xor(l_part, 16);
    l_part += __shfl_xor(l_part, 32);
    float invl[4];
    #pragma unroll
    for (int r = 0; r < 4; r++)
        invl[r] = 1.f / __shfl(l_part, quad * 4 + r);

    const int row0 = b * NN + qtile * 64 + (wave & 3) * 16 + quad * 4;
    #pragma unroll
    for (int r = 0; r < 4; r++) {
        us* dst = Ao + (size_t)(row0 + r) * INNER + h * DH + l16;
        #pragma unroll
        for (int t2 = 0; t2 < 8; t2++)
            dst[t2 * 16] = f2bfb(Oacc[t2][r] * invl[r]);
    }
}

// ---------------------------------------------------------------------------
extern "C" void kernel_launch(void* const* d_in, const int* in_sizes, int n_in,
                              void* d_out, int out_size, void* d_ws, size_t ws_size,
                              hipStream_t stream)
{
    const float* x      = (const float*)d_in[0];
    const float* past_k = (const float*)d_in[1];
    const float* past_v = (const float*)d_in[2];
    // d_in[3] = mask (unused; computed analytically)
    const float* w_qkv  = (const float*)d_in[4];
    const float* w_out  = (const float*)d_in[5];
    const float* ln_g   = (const float*)d_in[6];
    const float* ln_b   = (const float*)d_in[7];

    float* out   = (float*)d_out;                      // [B,N,DIM]
    float* out_k = out   + (size_t)BB * NN * DIM;      // [B,H,KVL,DH]
    float* out_v = out_k + (size_t)BB * HEADS * KVL * DH;

    // ws (bf16 buffers), 80 MB total:
    us* xn   = (us*)d_ws;                              // [TOK][DIM]     8 MB
    us* qkv  = xn  + (size_t)TOK * DIM;                // [TOK][NQKV]   24 MB
    us* Wqt  = qkv + (size_t)TOK * NQKV;               // [NQKV][DIM]   24 MB
    us* Wot  = Wqt + (size_t)NQKV * DIM;               // [DIM][INNER]   8 MB
    us* Vtg  = Wot + (size_t)DIM * INNER;              // [bh][DH][KVL] 16 MB
    us* attn = xn;   // alias: xn dead after qkv GEMM  // [TOK][INNER]   8 MB
    us* Kbf  = Wqt;  // alias: Wqt dead after qkv GEMM // [bh][KVL][DH] 16.7 MB

    transp_kernel<<<dim3(NQKV / 64, DIM / 64), 256, 0, stream>>>(
        w_qkv, Wqt, DIM, NQKV);
    transp_kernel<<<dim3(DIM / 64, INNER / 64), 256, 0, stream>>>(
        w_out, Wot, INNER, DIM);

    ln_kernel<<<TOK, 256, 0, stream>>>(x, ln_g, ln_b, xn);

    gemm_bt_kernel<true><<<dim3(NQKV / 128, TOK / 128), 256, 0, stream>>>(
        xn, Wqt, (void*)qkv, TOK, NQKV, DIM);

    rope_kernel<<<(BB * HEADS * KVL) / 4, 256, 0, stream>>>(
        past_k, past_v, qkv, out_k, out_v, Kbf);

    vtrans_kernel<<<dim3(KVL / 64, DH / 64, BB * HEADS), 256, 0, stream>>>(
        out_v, Vtg);

    attn_mfma_kernel<<<256, 512, 0, stream>>>(
        qkv, Kbf, Vtg, attn);

    gemm_bt_kernel<false><<<dim3(DIM / 128, TOK / 128), 256, 0, stream>>>(
        attn, Wot, (void*)out, TOK, DIM, INNER);
}